// Round 5
// baseline (312.862 us; speedup 1.0000x reference)
//
#include <hip/hip_runtime.h>

#define D_MODEL 1024
#define VOCAB   50257

typedef const __attribute__((address_space(1))) void* gptr_t;
typedef __attribute__((address_space(3))) void*       lptr_t;

// One wave (64-thread block) per (row, 4-level group). Grid = B * NG.
// The wave stages its 4 gathered weight rows (16 KB) into LDS via 16 async
// global_load_lds (width=16) -- in-flight bytes no longer limited by VGPRs
// (10 blocks/CU resident => up to 160 KB/CU outstanding). Input row lives in
// 16 VGPRs/lane. One s_waitcnt vmcnt(0); no barriers (producer wave ==
// consumer wave). 6-shfl reduce-scatter gives each 16-lane group one level's
// full dot; lane-parallel log-sigmoid; 2 shfls; one fp32 atomicAdd per wave.
__global__ __launch_bounds__(64) void hs_kernel(
    const float* __restrict__ input,       // [B, D_MODEL]
    const float* __restrict__ W,           // [VOCAB-1, D_MODEL]
    const int*   __restrict__ path_nodes,  // [VOCAB, Dmax]
    const float* __restrict__ path_signs,  // [VOCAB, Dmax]
    const int*   __restrict__ target,      // [B]
    float*       __restrict__ out,         // [B] (pre-zeroed)
    int Dmax, int NG)
{
    __shared__ float lds_w[4 * D_MODEL];   // 16 KB

    const int blk  = blockIdx.x;
    const int row  = blk / NG;
    const int base = (blk - row * NG) * 4; // first level this wave owns
    const int lane = threadIdx.x;

    const int t = target[row];

    // 4 node ids (wave-uniform broadcast loads; clamp padding levels).
    int nodes[4];
    #pragma unroll
    for (int j = 0; j < 4; ++j) {
        int k = base + j;
        if (k > Dmax - 1) k = Dmax - 1;
        nodes[j] = path_nodes[t * Dmax + k];
    }

    // Async-stage 4 weight rows -> LDS (4 x 1KB chunks each).
    #pragma unroll
    for (int j = 0; j < 4; ++j) {
        const float* src = W + (size_t)nodes[j] * D_MODEL + lane * 4;
        char* dst = (char*)&lds_w[j * D_MODEL];
        #pragma unroll
        for (int c = 0; c < 4; ++c) {
            __builtin_amdgcn_global_load_lds((gptr_t)(src + c * 256),
                                             (lptr_t)(dst + c * 1024),
                                             16, 0, 0);
        }
    }

    // Input row into registers (also counted by vmcnt).
    const float4* x4 = reinterpret_cast<const float4*>(input + (size_t)row * D_MODEL);
    float4 xr0 = x4[lane];
    float4 xr1 = x4[lane + 64];
    float4 xr2 = x4[lane + 128];
    float4 xr3 = x4[lane + 192];

    asm volatile("s_waitcnt vmcnt(0)" ::: "memory");
    __builtin_amdgcn_sched_barrier(0);

    float v[4];
    #pragma unroll
    for (int j = 0; j < 4; ++j) {
        const float4* wr = reinterpret_cast<const float4*>(&lds_w[j * D_MODEL]);
        const float4 w0 = wr[lane];
        const float4 w1 = wr[lane + 64];
        const float4 w2 = wr[lane + 128];
        const float4 w3 = wr[lane + 192];
        v[j] = xr0.x * w0.x + xr0.y * w0.y + xr0.z * w0.z + xr0.w * w0.w
             + xr1.x * w1.x + xr1.y * w1.y + xr1.z * w1.z + xr1.w * w1.w
             + xr2.x * w2.x + xr2.y * w2.y + xr2.z * w2.z + xr2.w * w2.w
             + xr3.x * w3.x + xr3.y * w3.y + xr3.z * w3.z + xr3.w * w3.w;
    }

    // Reduce-scatter: 16-lane group g=(lane>>4)&3 ends with level base+g's
    // full 64-lane dot (verified absmax 0.0 in R4).
    const bool b5 = (lane & 32) != 0;
    const bool b4 = (lane & 16) != 0;
    const float t0 = b5 ? v[0] : v[2];
    const float t1 = b5 ? v[1] : v[3];
    const float r0 = __shfl_xor(t0, 32);
    const float r1 = __shfl_xor(t1, 32);
    const float a  = (b5 ? v[2] : v[0]) + r0;
    const float c  = (b5 ? v[3] : v[1]) + r1;
    const float tt = b4 ? a : c;
    const float rr = __shfl_xor(tt, 16);
    float s = (b4 ? c : a) + rr;
    s += __shfl_xor(s, 8);
    s += __shfl_xor(s, 4);
    s += __shfl_xor(s, 2);
    s += __shfl_xor(s, 1);

    const int kk = base + ((lane >> 4) & 3);
    const float sgn = (kk < Dmax) ? path_signs[t * Dmax + kk] : 0.0f;
    float term = 0.0f;
    if (sgn != 0.0f) {
        const float z = sgn * s;
        term = fminf(z, 0.0f) - log1pf(expf(-fabsf(z)));
    }
    term += __shfl_xor(term, 16);
    term += __shfl_xor(term, 32);

    if (lane == 0) atomicAdd(&out[row], term);
}

extern "C" void kernel_launch(void* const* d_in, const int* in_sizes, int n_in,
                              void* d_out, int out_size, void* d_ws, size_t ws_size,
                              hipStream_t stream) {
    const float* input      = (const float*)d_in[0];
    const float* W          = (const float*)d_in[1];
    const int*   path_nodes = (const int*)d_in[2];
    const float* path_signs = (const float*)d_in[3];
    const int*   target     = (const int*)d_in[4];
    float*       out        = (float*)d_out;

    const int B    = in_sizes[4];
    const int Dmax = in_sizes[2] / VOCAB;
    const int NG   = (Dmax + 3) / 4;

    hipMemsetAsync(d_out, 0, (size_t)out_size * sizeof(float), stream);
    hs_kernel<<<B * NG, 64, 0, stream>>>(input, W, path_nodes, path_signs,
                                         target, out, Dmax, NG);
}